// Round 10
// baseline (188.255 us; speedup 1.0000x reference)
//
#include <hip/hip_runtime.h>
#include <hip/hip_bf16.h>

// MoE top-2 dispatch -> pair-binned grouped GEMM (bf16 MFMA) -> single-store combine.
// 3 launches:
//   0. memsetAsync cnt[64]
//   1. prep (role-split): route (LDS-histogram) | cvt_x (bf16) | cvt_wt (transpose)
//   2. moe_gemm: TALL-WAVE geometry on the proven 2-barrier core:
//      block 128x256, 4 waves side by side; each wave computes 128x64
//      (acc[8][4], 128 VGPRs) and shares the whole A-tile (broadcast ds_read).
//      ds_read bytes/MFMA: 7.2 (R6 80x64 wave) -> 6.0; gloads/out -35%.
//      Schedule = R2/R6-proven single-buffer: STAGE -> bar -> 64 MFMA -> bar.
//      pass0 = x*W[e1]; acc *= r=g1/g2; pass1 += x*W[e2]; out = s*(acc+r*b1+b2).

#define TOK 16384
#define DD  1024
#define OO  1024
#define NE  8
#define NBIN 64
#define MAXT 192   // sum ceil(cnt_p/128) <= 16384/128 + 64 = 192; 192%8==0 (XCD)
#define BM  128
#define BN  256
#define BK  64

typedef __bf16 bf16x8 __attribute__((ext_vector_type(8)));
typedef float  f32x4  __attribute__((ext_vector_type(4)));

__device__ __forceinline__ unsigned short f2bf(float f) {
  unsigned u = __float_as_uint(f);
  u += 0x7fffu + ((u >> 16) & 1u);   // RNE
  return (unsigned short)(u >> 16);
}

__device__ __forceinline__ void gload_lds16(const void* g, void* l) {
  __builtin_amdgcn_global_load_lds(
      (const __attribute__((address_space(1))) void*)g,
      (__attribute__((address_space(3))) void*)l, 16, 0, 0);
}

// ---------------- fused prep (proven) ----------------
#define PREP_ROUTE_B 64
#define PREP_CVTX_B  4096
#define PREP_CVTW_B  2048

__global__ __launch_bounds__(256) void prep(
    const float* __restrict__ x, const float* __restrict__ gates,
    const float* __restrict__ W,
    unsigned short* __restrict__ xs, unsigned short* __restrict__ wtb,
    int* __restrict__ cnt, int* __restrict__ idx, float2* __restrict__ gp) {
  __shared__ float tile[64][65];
  int bid = blockIdx.x;

  if (bid < PREP_ROUTE_B) {
    __shared__ int h[NBIN];
    __shared__ int gbase[NBIN];
    if (threadIdx.x < NBIN) h[threadIdx.x] = 0;
    __syncthreads();
    int i = bid * 256 + threadIdx.x;
    int e1 = -1, e2 = -1; float g1 = 0.f, g2 = 0.f;
#pragma unroll
    for (int e = 0; e < NE; ++e) {
      float g = gates[i * NE + e];
      if (g > 0.f) { if (e1 < 0) { e1 = e; g1 = g; } else if (e2 < 0) { e2 = e; g2 = g; } }
    }
    float r, s; int pid = 0, rank = 0, valid = (e1 >= 0);
    if (valid) {
      if (e2 < 0) { e2 = e1; r = 1.f; s = 0.5f * g1; }
      else        { r = g1 / g2; s = g2; }
      pid = e1 * NE + e2;
      rank = atomicAdd(&h[pid], 1);
    } else { r = 0.f; s = 0.f; }
    __syncthreads();
    if (threadIdx.x < NBIN && h[threadIdx.x] > 0)
      gbase[threadIdx.x] = atomicAdd(cnt + threadIdx.x, h[threadIdx.x]);
    __syncthreads();
    if (valid) {
      int pos = gbase[pid] + rank;
      idx[pid * TOK + pos] = i;
      gp[(size_t)pid * TOK + pos] = make_float2(r, s);
    }

  } else if (bid < PREP_ROUTE_B + PREP_CVTX_B) {
    size_t base = (size_t)(bid - PREP_ROUTE_B) * 1024 + threadIdx.x;  // float4 units
    const float4* xp = (const float4*)x;
#pragma unroll
    for (int q = 0; q < 4; ++q) {
      float4 v = xp[base + q * 256];
      alignas(8) unsigned short o4[4] = {f2bf(v.x), f2bf(v.y), f2bf(v.z), f2bf(v.w)};
      *(uint2*)(xs + (base + q * 256) * 4) = *(const uint2*)o4;
    }

  } else {
    int wb = bid - (PREP_ROUTE_B + PREP_CVTX_B);
    int e = wb >> 8, tt = wb & 255;
    int d0 = (tt >> 4) * 64, o0 = (tt & 15) * 64;
    const float* src = W + ((size_t)e << 20) + (size_t)d0 * OO + o0;
    for (int i = threadIdx.x; i < 1024; i += 256) {
      int r = i >> 4, c4 = (i & 15) * 4;
      float4 v = *(const float4*)(src + (size_t)r * OO + c4);
      tile[r][c4 + 0] = v.x; tile[r][c4 + 1] = v.y;
      tile[r][c4 + 2] = v.z; tile[r][c4 + 3] = v.w;
    }
    __syncthreads();
    unsigned short* dst = wtb + ((size_t)e << 20) + (size_t)o0 * DD + d0;
    for (int i = threadIdx.x; i < 512; i += 256) {
      int o = i >> 3, d8 = (i & 7) * 8;
      alignas(16) unsigned short w8[8];
#pragma unroll
      for (int j = 0; j < 8; ++j) w8[j] = f2bf(tile[d8 + j][o]);
      *(uint4*)(dst + (size_t)o * DD + d8) = *(const uint4*)w8;
    }
  }
}

// ---------------- grouped GEMM: tall-wave 128x64, proven 2-barrier core ------
__global__ __launch_bounds__(256) void moe_gemm(
    const unsigned short* __restrict__ xs,
    const unsigned short* __restrict__ wtb, const int* __restrict__ idx,
    const float2* __restrict__ gp, const int* __restrict__ cnt,
    const float* __restrict__ bias, float* __restrict__ out) {
  __shared__ unsigned short As[BM * BK];   // 16 KB (shared by all 4 waves)
  __shared__ unsigned short Bs[BN * BK];   // 32 KB
  __shared__ int    rowsS[BM];
  __shared__ float2 gS[BM];
  __shared__ int    sPid, sLt, sCnt;

  // derive (pid, local tile) from cnt[] with a 64-lane prefix scan
  if (threadIdx.x < 64) {
    int lane = threadIdx.x;
    if (lane == 0) sPid = -1;
    int c = cnt[lane];
    int n = (c + BM - 1) >> 7;
    int pre = n;
#pragma unroll
    for (int o = 1; o < 64; o <<= 1) {
      int v = __shfl_up(pre, o);
      if (lane >= o) pre += v;
    }
    int lo = pre - n;
    int tb = blockIdx.x;                      // grid.x = tile index
    if (tb >= lo && tb < pre) { sPid = lane; sLt = tb - lo; sCnt = c; }
  }
  __syncthreads();
  int pid = sPid;
  if (pid < 0) return;
  int lt = sLt, cntv = sCnt;
  int e1 = pid >> 3, e2 = pid & 7;
  int n0 = blockIdx.y * BN;                   // grid.y = output column block

  int t = threadIdx.x, lane = t & 63, w = t >> 6;   // w in 0..3
  if (t < BM) {
    int slot = lt * BM + t;
    int tok = 0; float2 g = make_float2(0.f, 0.f);
    if (slot < cntv) { tok = idx[pid * TOK + slot]; g = gp[(size_t)pid * TOK + slot]; }
    rowsS[t] = tok; gS[t] = g;
  }
  __syncthreads();

  // staging source pointers (pre-swizzled global column: linear LDS dest +
  // swizzled ds_read form the same involution; chunk ^= (row&7))
  const unsigned short* aP[4];
  const unsigned short* bP[8];
  int csrc = (((lane & 7) ^ (lane >> 3)) << 3);   // staged rows have row&7 == lane>>3
#pragma unroll
  for (int it = 0; it < 4; ++it) {
    int r = (w * 4 + it) * 8 + (lane >> 3);      // A tile row this lane stages (<128)
    aP[it] = xs + (size_t)rowsS[r] * DD + csrc;
  }
#pragma unroll
  for (int it = 0; it < 8; ++it) {
    int r = (w * 8 + it) * 8 + (lane >> 3);      // B tile row (<256)
    bP[it] = wtb + ((size_t)e1 * OO + n0 + r) * DD + csrc;
  }
  const ptrdiff_t bAdv = (ptrdiff_t)(e2 - e1) * OO * DD;    // W[e1] -> W[e2]

  int hi = lane >> 4, lo = lane & 15;
  int aOff[8][2], bOff[4][2];
#pragma unroll
  for (int m = 0; m < 8; ++m) {
    int arow = m * 16 + lo;                      // all waves share full A tile
#pragma unroll
    for (int ks = 0; ks < 2; ++ks)
      aOff[m][ks] = arow * BK + ((((ks << 2) + hi) ^ (arow & 7)) << 3);
  }
#pragma unroll
  for (int n = 0; n < 4; ++n) {
    int brow = w * 64 + n * 16 + lo;             // wave's 64-col slab
#pragma unroll
    for (int ks = 0; ks < 2; ++ks)
      bOff[n][ks] = brow * BK + ((((ks << 2) + hi) ^ (brow & 7)) << 3);
  }

  f32x4 acc[8][4] = {};

#pragma unroll 1
  for (int g = 0; g < 32; ++g) {
    int k0 = (g & 15) << 6;
    const ptrdiff_t badd = (g & 16) ? bAdv : 0;
#pragma unroll
    for (int it = 0; it < 4; ++it)
      gload_lds16(aP[it] + k0, As + (((w << 2) + it) << 9));
#pragma unroll
    for (int it = 0; it < 8; ++it)
      gload_lds16(bP[it] + badd + k0, Bs + (((w << 3) + it) << 9));
    __syncthreads();   // compiler drains vmcnt before s_barrier
#pragma unroll
    for (int ks = 0; ks < 2; ++ks) {
      bf16x8 af[8], bfr[4];
#pragma unroll
      for (int m = 0; m < 8; ++m) af[m] = *(const bf16x8*)(As + aOff[m][ks]);
#pragma unroll
      for (int n = 0; n < 4; ++n) bfr[n] = *(const bf16x8*)(Bs + bOff[n][ks]);
#pragma unroll
      for (int m = 0; m < 8; ++m)
#pragma unroll
        for (int n = 0; n < 4; ++n)
          acc[m][n] = __builtin_amdgcn_mfma_f32_16x16x32_bf16(af[m], bfr[n], acc[m][n], 0, 0, 0);
    }
    if (g == 15) {
      // pass boundary: acc := r*(x*W1); pass1 adds x*W2
#pragma unroll
      for (int m = 0; m < 8; ++m) {
        float rr[4];
#pragma unroll
        for (int j = 0; j < 4; ++j) rr[j] = gS[m * 16 + hi * 4 + j].x;
#pragma unroll
        for (int n = 0; n < 4; ++n)
#pragma unroll
          for (int j = 0; j < 4; ++j) acc[m][n][j] *= rr[j];
      }
    }
    __syncthreads();
  }

  // epilogue: out = s*(acc + r*b1 + b2)
  const float* b1 = bias + e1 * OO;
  const float* b2 = bias + e2 * OO;
  float b1v[4], b2v[4];
#pragma unroll
  for (int n = 0; n < 4; ++n) {
    int col = n0 + w * 64 + n * 16 + lo;
    b1v[n] = b1[col]; b2v[n] = b2[col];
  }
#pragma unroll
  for (int m = 0; m < 8; ++m) {
#pragma unroll
    for (int j = 0; j < 4; ++j) {
      int rl = m * 16 + hi * 4 + j;   // C/D: row=(lane>>4)*4+reg, col=lane&15
      int slot = lt * BM + rl;
      if (slot < cntv) {
        float2 g = gS[rl];
        float* orow = out + (size_t)rowsS[rl] * OO + n0 + w * 64 + lo;
#pragma unroll
        for (int n = 0; n < 4; ++n)
          orow[n * 16] = g.y * (acc[m][n][j] + g.x * b1v[n] + b2v[n]);
      }
    }
  }
}

extern "C" void kernel_launch(void* const* d_in, const int* in_sizes, int n_in,
                              void* d_out, int out_size, void* d_ws, size_t ws_size,
                              hipStream_t stream) {
  const float* x     = (const float*)d_in[0];
  const float* gates = (const float*)d_in[1];
  const float* W     = (const float*)d_in[2];
  const float* bias  = (const float*)d_in[3];
  float* out = (float*)d_out;

  char* ws = (char*)d_ws;
  size_t off = 0;
  unsigned short* xs  = (unsigned short*)(ws + off); off += (size_t)TOK * DD * 2;
  unsigned short* wtb = (unsigned short*)(ws + off); off += (size_t)NE * DD * OO * 2;
  int*    idx  = (int*)(ws + off);    off += (size_t)NBIN * TOK * 4;
  float2* gp   = (float2*)(ws + off); off += (size_t)NBIN * TOK * 8;
  int*    cnt  = (int*)(ws + off);    off += NBIN * 4;
  if (ws_size < off) return;  // insufficient scratch (~60.5 MB needed)

  hipMemsetAsync(cnt, 0, NBIN * 4, stream);
  prep<<<PREP_ROUTE_B + PREP_CVTX_B + PREP_CVTW_B, 256, 0, stream>>>(
      x, gates, W, xs, wtb, cnt, idx, gp);
  dim3 gg(MAXT, OO / BN, 1);   // tile in x: 192%8==0 -> col-blocks share XCD
  moe_gemm<<<gg, 256, 0, stream>>>(xs, wtb, idx, gp, cnt, bias, out);
}

// Round 11
// 127.402 us; speedup vs baseline: 1.4776x; 1.4776x over previous
//
#include <hip/hip_runtime.h>
#include <hip/hip_bf16.h>

// MoE top-2 dispatch -> pair-binned grouped GEMM (bf16 MFMA) -> single-store combine.
// 3 launches (R6-proven optimum, 128.4us total; resubmitted after R7-R10
// schedule/geometry experiments all regressed: 8-phase 122-125us, B-in-reg 164us,
// tall-wave 165us — the 2-phase composite stall does not yield on this
// gathered-A grouped shape; see session record R4-R10):
//   0. memsetAsync cnt[64]
//   1. prep (role-split): route (LDS-histogram) | cvt_x (bf16) | cvt_wt (transpose)
//   2. moe_gemm: 160x128 tile, 4 waves, BK=64, double-buffered A+B in LDS,
//      one syncthreads per k-step with STAGE(t+1) issued after it,
//      grid=(168,8) XCD-co-located (168%8==0).
//      pass0 = x*W[e1]; acc *= r=g1/g2; pass1 += x*W[e2]; out = s*(acc+r*b1+b2).

#define TOK 16384
#define DD  1024
#define OO  1024
#define NE  8
#define NBIN 64
#define MAXT 168   // sum ceil(cnt_p/160) <= 166; 168%8==0 (XCD co-location)
#define BM  160
#define BN  128
#define BK  64

typedef __bf16 bf16x8 __attribute__((ext_vector_type(8)));
typedef float  f32x4  __attribute__((ext_vector_type(4)));

__device__ __forceinline__ unsigned short f2bf(float f) {
  unsigned u = __float_as_uint(f);
  u += 0x7fffu + ((u >> 16) & 1u);   // RNE
  return (unsigned short)(u >> 16);
}

__device__ __forceinline__ void gload_lds16(const void* g, void* l) {
  __builtin_amdgcn_global_load_lds(
      (const __attribute__((address_space(1))) void*)g,
      (__attribute__((address_space(3))) void*)l, 16, 0, 0);
}

// ---------------- fused prep ----------------
#define PREP_ROUTE_B 64
#define PREP_CVTX_B  4096
#define PREP_CVTW_B  2048

__global__ __launch_bounds__(256) void prep(
    const float* __restrict__ x, const float* __restrict__ gates,
    const float* __restrict__ W,
    unsigned short* __restrict__ xs, unsigned short* __restrict__ wtb,
    int* __restrict__ cnt, int* __restrict__ idx, float2* __restrict__ gp) {
  __shared__ float tile[64][65];
  int bid = blockIdx.x;

  if (bid < PREP_ROUTE_B) {
    // ---- route: LDS histogram -> one global reservation per bin per block ----
    __shared__ int h[NBIN];
    __shared__ int gbase[NBIN];
    if (threadIdx.x < NBIN) h[threadIdx.x] = 0;
    __syncthreads();
    int i = bid * 256 + threadIdx.x;
    int e1 = -1, e2 = -1; float g1 = 0.f, g2 = 0.f;
#pragma unroll
    for (int e = 0; e < NE; ++e) {
      float g = gates[i * NE + e];
      if (g > 0.f) { if (e1 < 0) { e1 = e; g1 = g; } else if (e2 < 0) { e2 = e; g2 = g; } }
    }
    float r, s; int pid = 0, rank = 0, valid = (e1 >= 0);
    if (valid) {
      if (e2 < 0) { e2 = e1; r = 1.f; s = 0.5f * g1; }
      else        { r = g1 / g2; s = g2; }
      pid = e1 * NE + e2;
      rank = atomicAdd(&h[pid], 1);
    } else { r = 0.f; s = 0.f; }
    __syncthreads();
    if (threadIdx.x < NBIN && h[threadIdx.x] > 0)
      gbase[threadIdx.x] = atomicAdd(cnt + threadIdx.x, h[threadIdx.x]);
    __syncthreads();
    if (valid) {
      int pos = gbase[pid] + rank;
      idx[pid * TOK + pos] = i;
      gp[(size_t)pid * TOK + pos] = make_float2(r, s);
    }

  } else if (bid < PREP_ROUTE_B + PREP_CVTX_B) {
    // ---- cvt_x: 16 elems/thread, per-instruction coalesced (16B ld / 8B st) ----
    size_t base = (size_t)(bid - PREP_ROUTE_B) * 1024 + threadIdx.x;  // float4 units
    const float4* xp = (const float4*)x;
#pragma unroll
    for (int q = 0; q < 4; ++q) {
      float4 v = xp[base + q * 256];
      alignas(8) unsigned short o4[4] = {f2bf(v.x), f2bf(v.y), f2bf(v.z), f2bf(v.w)};
      *(uint2*)(xs + (base + q * 256) * 4) = *(const uint2*)o4;
    }

  } else {
    // ---- cvt_wt: 64x64 transpose tile; float4 loads, 16B stores ----
    int wb = bid - (PREP_ROUTE_B + PREP_CVTX_B);
    int e = wb >> 8, tt = wb & 255;
    int d0 = (tt >> 4) * 64, o0 = (tt & 15) * 64;
    const float* src = W + ((size_t)e << 20) + (size_t)d0 * OO + o0;
    for (int i = threadIdx.x; i < 1024; i += 256) {
      int r = i >> 4, c4 = (i & 15) * 4;
      float4 v = *(const float4*)(src + (size_t)r * OO + c4);
      tile[r][c4 + 0] = v.x; tile[r][c4 + 1] = v.y;
      tile[r][c4 + 2] = v.z; tile[r][c4 + 3] = v.w;
    }
    __syncthreads();
    unsigned short* dst = wtb + ((size_t)e << 20) + (size_t)o0 * DD + d0;
    for (int i = threadIdx.x; i < 512; i += 256) {
      int o = i >> 3, d8 = (i & 7) * 8;
      alignas(16) unsigned short w8[8];
#pragma unroll
      for (int j = 0; j < 8; ++j) w8[j] = f2bf(tile[d8 + j][o]);
      *(uint4*)(dst + (size_t)o * DD + d8) = *(const uint4*)w8;
    }
  }
}

// ---------------- grouped GEMM (R4/R6-proven core) ----------------
__global__ __launch_bounds__(256) void moe_gemm(
    const unsigned short* __restrict__ xs,
    const unsigned short* __restrict__ wtb, const int* __restrict__ idx,
    const float2* __restrict__ gp, const int* __restrict__ cnt,
    const float* __restrict__ bias, float* __restrict__ out) {
  __shared__ unsigned short As[2 * BM * BK];   // 40 KB (double-buffered)
  __shared__ unsigned short Bs[2 * BN * BK];   // 32 KB
  __shared__ int    rowsS[BM];
  __shared__ float2 gS[BM];
  __shared__ int    sPid, sLt, sCnt;

  // derive (pid, local tile) from cnt[] with a 64-lane prefix scan
  if (threadIdx.x < 64) {
    int lane = threadIdx.x;
    if (lane == 0) sPid = -1;
    int c = cnt[lane];
    int n = (c + BM - 1) / BM;
    int pre = n;
#pragma unroll
    for (int o = 1; o < 64; o <<= 1) {
      int v = __shfl_up(pre, o);
      if (lane >= o) pre += v;
    }
    int lo = pre - n;
    int tb = blockIdx.x;                      // grid.x = tile index
    if (tb >= lo && tb < pre) { sPid = lane; sLt = tb - lo; sCnt = c; }
  }
  __syncthreads();
  int pid = sPid;
  if (pid < 0) return;
  int lt = sLt, cntv = sCnt;
  int e1 = pid >> 3, e2 = pid & 7;
  int n0 = blockIdx.y * BN;                   // grid.y = output column block

  int t = threadIdx.x, lane = t & 63, w = t >> 6;
  if (t < BM) {
    int slot = lt * BM + t;
    int tok = 0; float2 g = make_float2(0.f, 0.f);
    if (slot < cntv) { tok = idx[pid * TOK + slot]; g = gp[(size_t)pid * TOK + slot]; }
    rowsS[t] = tok; gS[t] = g;
  }
  __syncthreads();

  // staging source pointers (pre-swizzled global column: linear LDS dest +
  // swizzled ds_read form the same involution; chunk ^= (row&7))
  const unsigned short* aP[5];
  const unsigned short* bP[4];
  int csrc = (((lane & 7) ^ (lane >> 3)) << 3);   // staged rows have row&7 == lane>>3
#pragma unroll
  for (int it = 0; it < 5; ++it) {
    int r = (w * 5 + it) * 8 + (lane >> 3);      // A tile row this lane stages (<160)
    aP[it] = xs + (size_t)rowsS[r] * DD + csrc;
  }
#pragma unroll
  for (int it = 0; it < 4; ++it) {
    int r = (w * 4 + it) * 8 + (lane >> 3);      // B tile row (<128)
    bP[it] = wtb + ((size_t)e1 * OO + n0 + r) * DD + csrc;
  }
  const ptrdiff_t bAdv = (ptrdiff_t)(e2 - e1) * OO * DD;    // W[e1] -> W[e2]

  int wm = w >> 1, wn = w & 1;
  int hi = lane >> 4, lo = lane & 15;
  int aOff[5][2], bOff[4][2];
#pragma unroll
  for (int m = 0; m < 5; ++m) {
    int arow = wm * 80 + m * 16 + lo;
#pragma unroll
    for (int ks = 0; ks < 2; ++ks)
      aOff[m][ks] = arow * BK + ((((ks << 2) + hi) ^ (arow & 7)) << 3);
  }
#pragma unroll
  for (int n = 0; n < 4; ++n) {
    int brow = wn * 64 + n * 16 + lo;
#pragma unroll
    for (int ks = 0; ks < 2; ++ks)
      bOff[n][ks] = brow * BK + ((((ks << 2) + hi) ^ (brow & 7)) << 3);
  }

  // stage k-step g (g in [0,32): pass = g>>4, k0 = (g&15)*64) into buffer buf
  auto STAGE = [&](int g, int buf) {
    int k0 = (g & 15) << 6;
    int aB = buf * (BM * BK), bB = buf * (BN * BK);
    const ptrdiff_t badd = (g & 16) ? bAdv : 0;
#pragma unroll
    for (int it = 0; it < 5; ++it)
      gload_lds16(aP[it] + k0, As + aB + (((w * 5) + it) << 9));
#pragma unroll
    for (int it = 0; it < 4; ++it)
      gload_lds16(bP[it] + badd + k0, Bs + bB + (((w << 2) + it) << 9));
  };

  f32x4 acc[5][4] = {};

  STAGE(0, 0);
#pragma unroll 1
  for (int g = 0; g < 32; ++g) {
    int cur = g & 1;
    __syncthreads();                 // drains STAGE(g); prefetch from g-1 landed
    if (g < 31) STAGE(g + 1, cur ^ 1);   // in flight across this step's MFMAs
    int aB = cur * (BM * BK), bB = cur * (BN * BK);
#pragma unroll
    for (int ks = 0; ks < 2; ++ks) {
      bf16x8 af[5], bfr[4];
#pragma unroll
      for (int m = 0; m < 5; ++m) af[m] = *(const bf16x8*)(As + aB + aOff[m][ks]);
#pragma unroll
      for (int n = 0; n < 4; ++n) bfr[n] = *(const bf16x8*)(Bs + bB + bOff[n][ks]);
#pragma unroll
      for (int m = 0; m < 5; ++m)
#pragma unroll
        for (int n = 0; n < 4; ++n)
          acc[m][n] = __builtin_amdgcn_mfma_f32_16x16x32_bf16(af[m], bfr[n], acc[m][n], 0, 0, 0);
    }
    if (g == 15) {
      // pass boundary: acc := r*(x*W1); pass1 adds x*W2
#pragma unroll
      for (int m = 0; m < 5; ++m) {
        float rr[4];
#pragma unroll
        for (int j = 0; j < 4; ++j) rr[j] = gS[wm * 80 + m * 16 + hi * 4 + j].x;
#pragma unroll
        for (int n = 0; n < 4; ++n)
#pragma unroll
          for (int j = 0; j < 4; ++j) acc[m][n][j] *= rr[j];
      }
    }
  }

  // epilogue: out = s*(acc + r*b1 + b2)
  const float* b1 = bias + e1 * OO;
  const float* b2 = bias + e2 * OO;
  float b1v[4], b2v[4];
#pragma unroll
  for (int n = 0; n < 4; ++n) {
    int col = n0 + wn * 64 + n * 16 + lo;
    b1v[n] = b1[col]; b2v[n] = b2[col];
  }
#pragma unroll
  for (int m = 0; m < 5; ++m) {
#pragma unroll
    for (int j = 0; j < 4; ++j) {
      int rl = wm * 80 + m * 16 + hi * 4 + j;   // C/D: row=(lane>>4)*4+reg, col=lane&15
      int slot = lt * BM + rl;
      if (slot < cntv) {
        float2 g = gS[rl];
        float* orow = out + (size_t)rowsS[rl] * OO + n0 + wn * 64 + lo;
#pragma unroll
        for (int n = 0; n < 4; ++n)
          orow[n * 16] = g.y * (acc[m][n][j] + g.x * b1v[n] + b2v[n]);
      }
    }
  }
}

extern "C" void kernel_launch(void* const* d_in, const int* in_sizes, int n_in,
                              void* d_out, int out_size, void* d_ws, size_t ws_size,
                              hipStream_t stream) {
  const float* x     = (const float*)d_in[0];
  const float* gates = (const float*)d_in[1];
  const float* W     = (const float*)d_in[2];
  const float* bias  = (const float*)d_in[3];
  float* out = (float*)d_out;

  char* ws = (char*)d_ws;
  size_t off = 0;
  unsigned short* xs  = (unsigned short*)(ws + off); off += (size_t)TOK * DD * 2;
  unsigned short* wtb = (unsigned short*)(ws + off); off += (size_t)NE * DD * OO * 2;
  int*    idx  = (int*)(ws + off);    off += (size_t)NBIN * TOK * 4;
  float2* gp   = (float2*)(ws + off); off += (size_t)NBIN * TOK * 8;
  int*    cnt  = (int*)(ws + off);    off += NBIN * 4;
  if (ws_size < off) return;  // insufficient scratch (~60.5 MB needed)

  hipMemsetAsync(cnt, 0, NBIN * 4, stream);
  prep<<<PREP_ROUTE_B + PREP_CVTX_B + PREP_CVTW_B, 256, 0, stream>>>(
      x, gates, W, xs, wtb, cnt, idx, gp);
  dim3 gg(MAXT, OO / BN, 1);   // tile in x: 168%8==0 -> col-blocks share XCD
  moe_gemm<<<gg, 256, 0, stream>>>(xs, wtb, idx, gp, cnt, bias, out);
}